// Round 18
// baseline (336.697 us; speedup 1.0000x reference)
//
#include <hip/hip_runtime.h>
#include <stdint.h>

// out[e,o] = sum_{i,h} A[e,i,h] * W[h,i,o],  A[e] = rbf[e] @ sph[e] @ m2[e]
// In-register-A fused design (R14 structure, failure modes fixed):
//   prolog: rs[e,i,k] -> LDS f16 (swizzled); ONE __syncthreads.
//   main: wave grid 4e x 2o (wave = 16 edges x 64 outputs). Per chunk c=(hw,i):
//     lane (lr,lg) produces its own MFMA A-fragment in registers (32 fdot2,
//     m2 slice in regs) -> 4 MFMA vs W3 chunk o-half (chunk-major, L1-shared).
//   NO s_A, 1 LDS read/chunk. Depth-2 even/odd bv prefetch (named regs,
//   use-then-clobber). Bare s_barrier per 2 chunks paces waves so W3 stays
//   L1-hot (no waitcnt drain -- rs is read-only after prolog, no LDS hazard).

#define EMB 128
#define INTERM 64
#define SPH_N 16
#define KMAX 8
#define OUTD 128
#define EB 64
#define NTHR 512

typedef __attribute__((ext_vector_type(8))) __fp16 f16x8;
typedef __attribute__((ext_vector_type(2))) __fp16 f16x2;
typedef __attribute__((ext_vector_type(4))) float f32x4;

#if defined(__has_builtin)
#if __has_builtin(__builtin_amdgcn_fdot2)
#define HAVE_FDOT2 1
#endif
#endif
#ifndef HAVE_FDOT2
#define HAVE_FDOT2 0
#endif

__device__ __forceinline__ unsigned short f32_to_f16u(float f) {
  union { f16x2 h; uint32_t u; } c; c.h = __builtin_amdgcn_cvt_pkrtz(f, f);
  return (unsigned short)(c.u & 0xffffu);
}
__device__ __forceinline__ uint32_t pk_f16(float lo, float hi) {
  union { f16x2 h; uint32_t u; } c; c.h = __builtin_amdgcn_cvt_pkrtz(lo, hi);
  return c.u;
}
__device__ __forceinline__ float dot2(f16x2 a, f16x2 b, float c) {
#if HAVE_FDOT2
  return __builtin_amdgcn_fdot2(a, b, c, false);
#else
  return c + (float)a[0] * (float)b[0] + (float)a[1] * (float)b[1];
#endif
}

__global__ void k_build_inv(const int* __restrict__ id_reduce,
                            const int* __restrict__ id_ragged,
                            int* __restrict__ inv, int nTrip, int E) {
  int t = blockIdx.x * blockDim.x + threadIdx.x;
  if (t >= nTrip) return;
  int e = id_reduce[t], k = id_ragged[t];
  if (e >= 0 && e < E && k >= 0 && k < KMAX) inv[e * KMAX + k] = t;
}

// chunk-major W repack: W3[c][o][j] = f16(W[h=(c>>6)*32+j][i=c&63][o]), c=0..255
__global__ void k_w3(const float* __restrict__ W, unsigned short* __restrict__ W3) {
  int idx = blockIdx.x * blockDim.x + threadIdx.x;  // [0, 256*128*32)
  int c = idx >> 12;
  int rem = idx & 4095;
  int o = rem >> 5, j = rem & 31;
  int h = ((c >> 6) << 5) + j, i = c & 63;
  W3[idx] = f32_to_f16u(W[((size_t)h * INTERM + i) * OUTD + o]);
}

// sphT[e][k][s] = sph[e][s][k]
__global__ void k_spht(const float* __restrict__ sph, float* __restrict__ sphT, int E) {
  int idx = blockIdx.x * blockDim.x + threadIdx.x;
  int e = idx >> 7, r = idx & 127;
  if (e >= E) return;
  int k = r >> 4, s = r & 15;
  sphT[(size_t)e * 128 + k * 16 + s] = sph[(size_t)e * 128 + s * 8 + k];
}

__global__ __launch_bounds__(NTHR, 4) void k_fused(
    const float* __restrict__ rbf,   // [E][64][16]
    const float* __restrict__ sphT,  // [E][8][16]
    const float* __restrict__ m,     // [nTrip][128]
    const int* __restrict__ inv,     // [Epad][8]
    const unsigned short* __restrict__ W3,  // [256][128][32] f16
    float* __restrict__ out, int E)
{
  __shared__ unsigned short s_rs[EB * 64 * 8];  // 64 KB, rs[e][i][k] f16 xor-swizzled

  int tid = threadIdx.x;
  int e0 = blockIdx.x * EB;

  // ---- prolog (R13-verified): thread (eL=tid>>3, kq=tid&7) writes rs[eL][all i][kq]
  {
    int eL = tid >> 3, kq = tid & 7;
    int egp = e0 + eL;
    bool evp = (egp < E);
    int esw8p = (eL & 7) << 3;
    f32x4 sp0 = 0.f, sp1 = 0.f, sp2 = 0.f, sp3 = 0.f;
    if (evp) {
      const f32x4* sp = (const f32x4*)(sphT + (size_t)egp * 128 + kq * 16);
      sp0 = sp[0]; sp1 = sp[1]; sp2 = sp[2]; sp3 = sp[3];
    }
    const f32x4* rb = (const f32x4*)(rbf + (size_t)egp * 1024);
#pragma unroll 4
    for (int i = 0; i < 64; ++i) {
      float v = 0.f;
      if (evp) {
        f32x4 q0 = rb[i * 4 + 0], q1 = rb[i * 4 + 1];
        f32x4 q2 = rb[i * 4 + 2], q3 = rb[i * 4 + 3];
        v = q0.x * sp0.x + q0.y * sp0.y + q0.z * sp0.z + q0.w * sp0.w
          + q1.x * sp1.x + q1.y * sp1.y + q1.z * sp1.z + q1.w * sp1.w
          + q2.x * sp2.x + q2.y * sp2.y + q2.z * sp2.z + q2.w * sp2.w
          + q3.x * sp3.x + q3.y * sp3.y + q3.z * sp3.z + q3.w * sp3.w;
      }
      s_rs[(eL << 9) + (((i << 3) ^ esw8p) | kq)] = f32_to_f16u(v);
    }
  }
  __syncthreads();   // rs handoff fence (only full barrier in the kernel)

  // ---- roles: 8 waves = 4e x 2o; wave tile 16 edges x 64 outputs
  int wid = tid >> 6, lane = tid & 63;
  int lr = lane & 15, lg = lane >> 4;
  int ew = wid >> 1, ow = wid & 1;
  int eg = e0 + ew * 16 + lr;          // edge this lane produces & consumes
  bool evm = (eg < E);
  int rsbase = ((ew * 16 + lr) << 9);
  int esw8 = (lr & 7) << 3;

  // triplet indices, hoisted once
  int tk[8];
  if (evm) {
    int4 a = *(const int4*)(inv + (size_t)eg * 8);
    int4 b = *(const int4*)(inv + (size_t)eg * 8 + 4);
    tk[0] = a.x; tk[1] = a.y; tk[2] = a.z; tk[3] = a.w;
    tk[4] = b.x; tk[5] = b.y; tk[6] = b.z; tk[7] = b.w;
  } else {
#pragma unroll
    for (int k = 0; k < 8; ++k) tk[k] = -1;
  }

  // m2 slice packed in k-pairs: m2p[j][kp] = (m2[2kp][h_j], m2[2kp+1][h_j]),
  // h_j = hw*32 + lg*8 + j
  f16x2 m2p[8][4];
  f32x4 acc0 = (f32x4){0.f,0.f,0.f,0.f}, acc1 = acc0, acc2 = acc0, acc3 = acc0;

  const unsigned short* wlane = W3 + (ow * 64 + lr) * 32 + lg * 8;

#define LOAD_M2(HW)                                                          \
  {                                                                          \
    int hoff = (HW) * 32 + lg * 8;                                           \
    _Pragma("unroll")                                                        \
    for (int kp = 0; kp < 4; ++kp) {                                         \
      int t0 = tk[2 * kp], t1 = tk[2 * kp + 1];                              \
      const float* p0 = m + (size_t)(t0 < 0 ? 0 : t0) * EMB + hoff;          \
      const float* p1 = m + (size_t)(t1 < 0 ? 0 : t1) * EMB + hoff;          \
      f32x4 lo0 = *(const f32x4*)p0, hi0 = *(const f32x4*)(p0 + 4);          \
      f32x4 lo1 = *(const f32x4*)p1, hi1 = *(const f32x4*)(p1 + 4);          \
      if (t0 < 0) { lo0 = (f32x4){0.f,0.f,0.f,0.f}; hi0 = lo0; }             \
      if (t1 < 0) { lo1 = (f32x4){0.f,0.f,0.f,0.f}; hi1 = lo1; }             \
      _Pragma("unroll")                                                      \
      for (int j = 0; j < 4; ++j) {                                          \
        m2p[j][kp]     = __builtin_amdgcn_cvt_pkrtz(lo0[j], lo1[j]);         \
        m2p[4 + j][kp] = __builtin_amdgcn_cvt_pkrtz(hi0[j], hi1[j]);         \
      }                                                                      \
    }                                                                        \
    asm volatile("" ::: "memory"); /* forbid sinking m-loads into i-loop */  \
  }

#define PRODUCE_AF(C, AFU)                                                   \
    union { uint4 u; f16x8 h; } AFU;                                         \
    {                                                                        \
      union { uint4 u; f16x2 p[4]; } rsu;                                    \
      rsu.u = *(const uint4*)&s_rs[rsbase + ((((C) & 63) << 3) ^ esw8)];     \
      float a0 = 0.f, a1 = 0.f, a2 = 0.f, a3 = 0.f;                          \
      float a4 = 0.f, a5 = 0.f, a6 = 0.f, a7 = 0.f;                          \
      _Pragma("unroll")                                                      \
      for (int kp = 0; kp < 4; ++kp) {                                       \
        a0 = dot2(rsu.p[kp], m2p[0][kp], a0);                                \
        a1 = dot2(rsu.p[kp], m2p[1][kp], a1);                                \
        a2 = dot2(rsu.p[kp], m2p[2][kp], a2);                                \
        a3 = dot2(rsu.p[kp], m2p[3][kp], a3);                                \
        a4 = dot2(rsu.p[kp], m2p[4][kp], a4);                                \
        a5 = dot2(rsu.p[kp], m2p[5][kp], a5);                                \
        a6 = dot2(rsu.p[kp], m2p[6][kp], a6);                                \
        a7 = dot2(rsu.p[kp], m2p[7][kp], a7);                                \
      }                                                                      \
      AFU.u.x = pk_f16(a0, a1); AFU.u.y = pk_f16(a2, a3);                    \
      AFU.u.z = pk_f16(a4, a5); AFU.u.w = pk_f16(a6, a7);                    \
    }

  // depth-2 bv prefetch: even chunks use bvA, odd use bvB (named, no movs)
  f16x8 bvA0, bvA1, bvA2, bvA3, bvB0, bvB1, bvB2, bvB3;
  {
    const unsigned short* wp = wlane;          // chunk 0
    bvA0 = *(const f16x8*)(wp);
    bvA1 = *(const f16x8*)(wp + 512);
    bvA2 = *(const f16x8*)(wp + 1024);
    bvA3 = *(const f16x8*)(wp + 1536);
    wp = wlane + 4096;                         // chunk 1
    bvB0 = *(const f16x8*)(wp);
    bvB1 = *(const f16x8*)(wp + 512);
    bvB2 = *(const f16x8*)(wp + 1024);
    bvB3 = *(const f16x8*)(wp + 1536);
  }

  LOAD_M2(0)
  for (int hw = 0; hw < 4; ++hw) {
    if (hw) { LOAD_M2(hw) }
#pragma unroll 1
    for (int ii = 0; ii < 64; ii += 2) {
      int c = hw * 64 + ii;
      {  // even chunk c: consume bvA, prefetch chunk c+2 into bvA
        PRODUCE_AF(c, afu)
        acc0 = __builtin_amdgcn_mfma_f32_16x16x32_f16(afu.h, bvA0, acc0, 0, 0, 0);
        acc1 = __builtin_amdgcn_mfma_f32_16x16x32_f16(afu.h, bvA1, acc1, 0, 0, 0);
        acc2 = __builtin_amdgcn_mfma_f32_16x16x32_f16(afu.h, bvA2, acc2, 0, 0, 0);
        acc3 = __builtin_amdgcn_mfma_f32_16x16x32_f16(afu.h, bvA3, acc3, 0, 0, 0);
        // prefetch (c+2 <= 257: OOB-by-<=2-chunks lands in sphT region, valid mem)
        const unsigned short* wpn = wlane + ((size_t)(c + 2) << 12);
        bvA0 = *(const f16x8*)(wpn);
        bvA1 = *(const f16x8*)(wpn + 512);
        bvA2 = *(const f16x8*)(wpn + 1024);
        bvA3 = *(const f16x8*)(wpn + 1536);
      }
      {  // odd chunk c+1: consume bvB, prefetch chunk c+3 into bvB
        PRODUCE_AF(c + 1, afv)
        acc0 = __builtin_amdgcn_mfma_f32_16x16x32_f16(afv.h, bvB0, acc0, 0, 0, 0);
        acc1 = __builtin_amdgcn_mfma_f32_16x16x32_f16(afv.h, bvB1, acc1, 0, 0, 0);
        acc2 = __builtin_amdgcn_mfma_f32_16x16x32_f16(afv.h, bvB2, acc2, 0, 0, 0);
        acc3 = __builtin_amdgcn_mfma_f32_16x16x32_f16(afv.h, bvB3, acc3, 0, 0, 0);
        const unsigned short* wpn = wlane + ((size_t)(c + 3) << 12);
        bvB0 = *(const f16x8*)(wpn);
        bvB1 = *(const f16x8*)(wpn + 512);
        bvB2 = *(const f16x8*)(wpn + 1024);
        bvB3 = *(const f16x8*)(wpn + 1536);
      }
      // bare pacing barrier: keeps waves within ~2 chunks so W3 stays L1-hot.
      // No waitcnt drain needed: no cross-wave LDS traffic in the main loop.
      __builtin_amdgcn_s_barrier();
    }
  }

  // ---- epilogue (R14-verified): col = ow*64 + t*16 + lr, row = e0+ew*16+lg*4+r
  {
    int ebase = e0 + ew * 16 + lg * 4;
#define STORE_T(OT, ACC)                                          \
    {                                                             \
      int o = ow * 64 + (OT) * 16 + lr;                           \
      _Pragma("unroll")                                           \
      for (int r = 0; r < 4; ++r) {                               \
        int e = ebase + r;                                        \
        if (e < E) out[(size_t)e * OUTD + o] = (ACC)[r];          \
      }                                                           \
    }
    STORE_T(0, acc0) STORE_T(1, acc1) STORE_T(2, acc2) STORE_T(3, acc3)
#undef STORE_T
  }
}

extern "C" void kernel_launch(void* const* d_in, const int* in_sizes, int n_in,
                              void* d_out, int out_size, void* d_ws, size_t ws_size,
                              hipStream_t stream) {
  const float* rbf = (const float*)d_in[0];
  const float* sph = (const float*)d_in[1];
  const float* m   = (const float*)d_in[2];
  const float* W   = (const float*)d_in[3];
  const int* id_reduce = (const int*)d_in[4];
  const int* id_ragged = (const int*)d_in[5];
  float* out = (float*)d_out;

  int E = in_sizes[0] / (INTERM * SPH_N);   // 30000
  int nTrip = in_sizes[2] / EMB;            // 240000
  int nblk = (E + EB - 1) / EB;             // 469
  int Epad = nblk * EB;                     // 30016

  char* ws = (char*)d_ws;
  int* inv = (int*)ws;                                       // [0, 1 MB)
  unsigned short* W3 = (unsigned short*)(ws + (1u << 20));   // [1, 3 MB)
  float* sphT = (float*)(ws + (3u << 20));                   // [3, ~18.4 MB)

  (void)hipMemsetAsync(inv, 0xFF, (size_t)Epad * KMAX * sizeof(int), stream);
  k_build_inv<<<(nTrip + 255) / 256, 256, 0, stream>>>(id_reduce, id_ragged, inv, nTrip, E);
  k_w3<<<(256 * 128 * 32) / 256, 256, 0, stream>>>(W, W3);
  k_spht<<<(E * 128 + 255) / 256, 256, 0, stream>>>(sph, sphT, E);

  k_fused<<<nblk, NTHR, 0, stream>>>(rbf, sphT, m, inv, W3, out, E);
}

// Round 19
// 316.848 us; speedup vs baseline: 1.0626x; 1.0626x over previous
//
#include <hip/hip_runtime.h>
#include <stdint.h>

// out[e,o] = sum_{i,h} A[e,i,h] * W[h,i,o],  A[e] = rbf[e] @ sph[e] @ m2[e]
// Fused. chunk c = (hw=c>>6, i=c&63), K=32/chunk; PERIOD = 2 chunks, ONE barrier.
// R19 vs R17: wave grid 1x8 -> 2e x 4o (af LDS traffic halves: 8 ds_read_b128 /
// period instead of 16+16... each wave reads only its 32 rows); bv = 4 regs,
// prefetched ONE FULL PERIOD ahead, single vmcnt(0) BEFORE the 8 MFMAs, prefetch
// issued strictly AFTER (fixes R16's misordered vmcnt that exposed L2 latency).

#define EMB 128
#define INTERM 64
#define SPH_N 16
#define KMAX 8
#define OUTD 128
#define KDIM 8192
#define EB 64
#define NTHR 512
#define NCHUNK 256

typedef __attribute__((ext_vector_type(8))) __fp16 f16x8;
typedef __attribute__((ext_vector_type(2))) __fp16 f16x2;
typedef __attribute__((ext_vector_type(4))) float f32x4;
typedef __attribute__((ext_vector_type(4))) int i32x4;

#if defined(__has_builtin)
#if __has_builtin(__builtin_amdgcn_fdot2)
#define HAVE_FDOT2 1
#endif
#endif
#ifndef HAVE_FDOT2
#define HAVE_FDOT2 0
#endif

__device__ __forceinline__ unsigned short f32_to_f16u(float f) {
  union { f16x2 h; uint32_t u; } c; c.h = __builtin_amdgcn_cvt_pkrtz(f, f);
  return (unsigned short)(c.u & 0xffffu);
}
__device__ __forceinline__ uint32_t pk_f16(float lo, float hi) {
  union { f16x2 h; uint32_t u; } c; c.h = __builtin_amdgcn_cvt_pkrtz(lo, hi);
  return c.u;
}
__device__ __forceinline__ f16x8 as_h16(f32x4 v) {
  union { f32x4 f; f16x8 h; } u; u.f = v; return u.h;
}
__device__ __forceinline__ float dot2(f16x2 a, f16x2 b, float c) {
#if HAVE_FDOT2
  return __builtin_amdgcn_fdot2(a, b, c, false);
#else
  return c + (float)a[0] * (float)b[0] + (float)a[1] * (float)b[1];
#endif
}
// W load: 32-bit lane voffset + uniform SGPR base
__device__ __forceinline__ void gload_bv(f32x4& d, const unsigned short* sbase, uint32_t voff) {
  asm volatile("global_load_dwordx4 %0, %1, %2" : "=&v"(d) : "v"(voff), "s"(sbase));
}

__global__ void k_build_inv(const int* __restrict__ id_reduce,
                            const int* __restrict__ id_ragged,
                            int* __restrict__ inv, int nTrip, int E) {
  int t = blockIdx.x * blockDim.x + threadIdx.x;
  if (t >= nTrip) return;
  int e = id_reduce[t], k = id_ragged[t];
  if (e >= 0 && e < E && k >= 0 && k < KMAX) inv[e * KMAX + k] = t;
}

// W (h,i,o) f32 -> W2T[o][c = i*128 + h] f16
__global__ void k_w2t(const float* __restrict__ W, unsigned short* __restrict__ W2T) {
  int idx = blockIdx.x * blockDim.x + threadIdx.x;  // [0, 128*8192)
  int o = idx >> 13;
  int c = idx & (KDIM - 1);
  int h = c & 127, i = c >> 7;
  W2T[idx] = f32_to_f16u(W[(h * INTERM + i) * OUTD + o]);
}

// sphT[e][k][s] = sph[e][s][k]
__global__ void k_spht(const float* __restrict__ sph, float* __restrict__ sphT, int E) {
  int idx = blockIdx.x * blockDim.x + threadIdx.x;  // [0, E*128)
  int e = idx >> 7, r = idx & 127;
  if (e >= E) return;
  int k = r >> 4, s = r & 15;
  sphT[(size_t)e * 128 + k * 16 + s] = sph[(size_t)e * 128 + s * 8 + k];
}

__global__ __launch_bounds__(NTHR, 2) void k_fused(
    const float* __restrict__ rbf,   // [E][64][16]
    const float* __restrict__ sphT,  // [E][8][16]
    const float* __restrict__ m,     // [nTrip][128]
    const int* __restrict__ inv,     // [Epad][8]
    const unsigned short* __restrict__ W2T,  // [128][8192] f16
    float* __restrict__ out, int E)
{
  __shared__ unsigned short s_rs[EB * 64 * 8];    // 64 KB, rs[e][i][k] f16 xor-swizzled
  __shared__ unsigned short s_A[2][2][EB * 32];   // 16 KB quad-buffer, XOR-swizzled

  int tid = threadIdx.x;
  int e0 = blockIdx.x * EB;
  int eL = tid >> 3;          // 0..63 edge-local
  int kq = tid & 7;           // prolog: k ; main: h-quarter (4 h)
  int hq = kq;
  int eg = e0 + eL;
  bool ev = (eg < E);
  int esw8 = (eL & 7) << 3;   // rs swizzle (ushort units)
  int asw  = (eL & 3) << 3;   // s_A write swizzle

  // ---- prolog: rs[eL][i][kq] for all i (f32 math, f16 store)
  {
    f32x4 sp0 = 0.f, sp1 = 0.f, sp2 = 0.f, sp3 = 0.f;
    if (ev) {
      const f32x4* sp = (const f32x4*)(sphT + (size_t)eg * 128 + kq * 16);
      sp0 = sp[0]; sp1 = sp[1]; sp2 = sp[2]; sp3 = sp[3];
    }
    const f32x4* rb = (const f32x4*)(rbf + (size_t)eg * 1024);
#pragma unroll 4
    for (int i = 0; i < 64; ++i) {
      float v = 0.f;
      if (ev) {
        f32x4 q0 = rb[i * 4 + 0], q1 = rb[i * 4 + 1];
        f32x4 q2 = rb[i * 4 + 2], q3 = rb[i * 4 + 3];
        v = q0.x * sp0.x + q0.y * sp0.y + q0.z * sp0.z + q0.w * sp0.w
          + q1.x * sp1.x + q1.y * sp1.y + q1.z * sp1.z + q1.w * sp1.w
          + q2.x * sp2.x + q2.y * sp2.y + q2.z * sp2.z + q2.w * sp2.w
          + q3.x * sp3.x + q3.y * sp3.y + q3.z * sp3.z + q3.w * sp3.w;
      }
      s_rs[(eL << 9) + (((i << 3) ^ esw8) | kq)] = f32_to_f16u(v);
    }
  }

  // ---- GEMM roles: 8 waves = 2e x 4o; wave tile 32e x 32o
  int wid = tid >> 6, lane = tid & 63;
  int lr = lane & 15, lg = lane >> 4;
  int ew = wid >> 2, ow = wid & 3;
  // af rows: ew*32+lr (frag0), +16 (frag1); (row&3)==(lr&3) so frag1 = frag0 + 512
  int aidx0 = ((ew * 32 + lr) << 5) + ((lg << 3) ^ ((lr & 3) << 3));
  int aidx1 = aidx0 + (16 << 5);
  uint32_t voff0 = (uint32_t)((((ow * 32 + lr) * KDIM) + lg * 8) * 2);
  uint32_t voff1 = voff0 + (uint32_t)(16 * KDIM * 2);
#define WBASE(N) (W2T + (((N) & 63) * 128 + (((N) >> 6) << 5)))

  // m2 packed in k-pairs: m2p[d][kp] = (m2[2kp][h_d], m2[2kp+1][h_d]), h_d = hw*32+hq*4+d
  f16x2 m2p[4][4];

#define LOAD_M2(HW)                                                              \
  {                                                                              \
    i32x4 iv0, iv1;                                                              \
    const int* ip_ = inv + (size_t)eg * 8;                                       \
    asm volatile("global_load_dwordx4 %0, %1, off" : "=&v"(iv0) : "v"(ip_));     \
    asm volatile("global_load_dwordx4 %0, %1, off" : "=&v"(iv1) : "v"(ip_ + 4)); \
    asm volatile("s_waitcnt vmcnt(0)" : "+v"(iv0), "+v"(iv1));                   \
    int tk_[8] = {iv0.x, iv0.y, iv0.z, iv0.w, iv1.x, iv1.y, iv1.z, iv1.w};       \
    f32x4 mm_[8];                                                                \
    _Pragma("unroll")                                                            \
    for (int k = 0; k < 8; ++k) {                                                \
      const float* mp_ = m + (size_t)(tk_[k] < 0 ? 0 : tk_[k]) * EMB             \
                         + (HW) * 32 + hq * 4;                                   \
      asm volatile("global_load_dwordx4 %0, %1, off" : "=&v"(mm_[k]) : "v"(mp_));\
    }                                                                            \
    asm volatile("s_waitcnt vmcnt(0)"                                            \
                 : "+v"(mm_[0]), "+v"(mm_[1]), "+v"(mm_[2]), "+v"(mm_[3]),       \
                   "+v"(mm_[4]), "+v"(mm_[5]), "+v"(mm_[6]), "+v"(mm_[7]));      \
    _Pragma("unroll")                                                            \
    for (int k = 0; k < 8; ++k)                                                  \
      if (tk_[k] < 0) mm_[k] = (f32x4){0.f, 0.f, 0.f, 0.f};                      \
    _Pragma("unroll")                                                            \
    for (int d = 0; d < 4; ++d) {                                                \
      _Pragma("unroll")                                                          \
      for (int kp = 0; kp < 4; ++kp)                                             \
        m2p[d][kp] = __builtin_amdgcn_cvt_pkrtz(mm_[2 * kp][d], mm_[2 * kp + 1][d]); \
    }                                                                            \
  }

#define PRODUCE(RR, PAR, SL)                                                 \
  {                                                                          \
    union { uint4 u; f16x2 p[4]; } rsu; rsu.u = (RR);                        \
    float a0 = 0.f, a1 = 0.f, a2 = 0.f, a3 = 0.f;                            \
    _Pragma("unroll")                                                        \
    for (int kp = 0; kp < 4; ++kp) {                                         \
      a0 = dot2(rsu.p[kp], m2p[0][kp], a0);                                  \
      a1 = dot2(rsu.p[kp], m2p[1][kp], a1);                                  \
      a2 = dot2(rsu.p[kp], m2p[2][kp], a2);                                  \
      a3 = dot2(rsu.p[kp], m2p[3][kp], a3);                                  \
    }                                                                        \
    uint32_t p0 = pk_f16(a0, a1), p1 = pk_f16(a2, a3);                       \
    *(uint2*)&s_A[PAR][SL][(eL << 5) + ((hq << 2) ^ asw)] =                  \
        make_uint2(p0, p1);                                                  \
  }

  f32x4 acc00 = {0.f, 0.f, 0.f, 0.f}, acc01 = acc00, acc10 = acc00, acc11 = acc00;
  f32x4 bvA0, bvA1, bvB0, bvB1;   // chunk-a o-frags, chunk-b o-frags
  uint4 rsA0, rsA1, rsB0, rsB1;

  LOAD_M2(0)
  {
    uint4 rs0 = *(const uint4*)&s_rs[(eL << 9) + esw8];
    uint4 rs1 = *(const uint4*)&s_rs[(eL << 9) + ((1 << 3) ^ esw8)];
    PRODUCE(rs0, 0, 0)
    PRODUCE(rs1, 0, 1)
  }
  rsA0 = *(const uint4*)&s_rs[(eL << 9) + ((2 << 3) ^ esw8)];
  rsA1 = *(const uint4*)&s_rs[(eL << 9) + ((3 << 3) ^ esw8)];
  gload_bv(bvA0, WBASE(0), voff0);
  gload_bv(bvA1, WBASE(0), voff1);
  gload_bv(bvB0, WBASE(1), voff0);
  gload_bv(bvB1, WBASE(1), voff1);
  asm volatile("s_waitcnt lgkmcnt(0)" ::: "memory");
  __builtin_amdgcn_s_barrier();

#define PERIOD(P, PAR, RSP0, RSP1, RSF0, RSF1, M2CHK, PROD, PF)                  \
  {                                                                              \
    const int c_ = 2 * (P);                                                      \
    f16x8 a00 = *(const f16x8*)&s_A[PAR][0][aidx0];                              \
    f16x8 a01 = *(const f16x8*)&s_A[PAR][0][aidx1];                              \
    f16x8 a10 = *(const f16x8*)&s_A[PAR][1][aidx0];                              \
    f16x8 a11 = *(const f16x8*)&s_A[PAR][1][aidx1];                              \
    if (PF) {                                                                    \
      RSF0 = *(const uint4*)&s_rs[(eL << 9) + ((((c_ + 4) & 63) << 3) ^ esw8)];  \
      RSF1 = *(const uint4*)&s_rs[(eL << 9) + ((((c_ + 5) & 63) << 3) ^ esw8)];  \
    }                                                                            \
    if (M2CHK && (((c_ + 2) & 63) == 0)) LOAD_M2((c_ + 2) >> 6)                  \
    if (PROD) { PRODUCE(RSP0, (PAR) ^ 1, 0) PRODUCE(RSP1, (PAR) ^ 1, 1) }        \
    /* single wait: all 4 bv landed (issued one full period ago) */              \
    asm volatile("s_waitcnt vmcnt(0)"                                            \
                 : "+v"(bvA0), "+v"(bvA1), "+v"(bvB0), "+v"(bvB1));              \
    {                                                                            \
      f16x8 b0 = as_h16(bvA0), b1 = as_h16(bvA1);                                \
      acc00 = __builtin_amdgcn_mfma_f32_16x16x32_f16(a00, b0, acc00, 0, 0, 0);   \
      acc01 = __builtin_amdgcn_mfma_f32_16x16x32_f16(a00, b1, acc01, 0, 0, 0);   \
      acc10 = __builtin_amdgcn_mfma_f32_16x16x32_f16(a01, b0, acc10, 0, 0, 0);   \
      acc11 = __builtin_amdgcn_mfma_f32_16x16x32_f16(a01, b1, acc11, 0, 0, 0);   \
      f16x8 c0 = as_h16(bvB0), c1 = as_h16(bvB1);                                \
      acc00 = __builtin_amdgcn_mfma_f32_16x16x32_f16(a10, c0, acc00, 0, 0, 0);   \
      acc01 = __builtin_amdgcn_mfma_f32_16x16x32_f16(a10, c1, acc01, 0, 0, 0);   \
      acc10 = __builtin_amdgcn_mfma_f32_16x16x32_f16(a11, c0, acc10, 0, 0, 0);   \
      acc11 = __builtin_amdgcn_mfma_f32_16x16x32_f16(a11, c1, acc11, 0, 0, 0);   \
    }                                                                            \
    /* prefetch next period STRICTLY AFTER the wait+MFMAs */                     \
    if (PF) {                                                                    \
      gload_bv(bvA0, WBASE(c_ + 2), voff0);                                      \
      gload_bv(bvA1, WBASE(c_ + 2), voff1);                                      \
      gload_bv(bvB0, WBASE(c_ + 3), voff0);                                      \
      gload_bv(bvB1, WBASE(c_ + 3), voff1);                                      \
    }                                                                            \
    asm volatile("s_waitcnt lgkmcnt(0)" ::: "memory");                           \
    __builtin_amdgcn_s_barrier();                                                \
  }

  for (int p = 0; p < 126; p += 2) {
    PERIOD(p,     0, rsA0, rsA1, rsB0, rsB1, 1, 1, 1)
    PERIOD(p + 1, 1, rsB0, rsB1, rsA0, rsA1, 1, 1, 1)
  }
  PERIOD(126, 0, rsA0, rsA1, rsB0, rsB1, 0, 1, 1)
  PERIOD(127, 1, rsB0, rsB1, rsA0, rsA1, 0, 0, 0)

  // ---- epilogue: C/D layout col = lane&15, row = (lane>>4)*4 + reg
  {
    int col0 = ow * 32 + lr, col1 = col0 + 16;
    int rbase = e0 + ew * 32 + lg * 4;
#pragma unroll
    for (int r = 0; r < 4; ++r) {
      int rA = rbase + r, rB = rbase + 16 + r;
      if (rA < E) {
        out[(size_t)rA * OUTD + col0] = acc00[r];
        out[(size_t)rA * OUTD + col1] = acc01[r];
      }
      if (rB < E) {
        out[(size_t)rB * OUTD + col0] = acc10[r];
        out[(size_t)rB * OUTD + col1] = acc11[r];
      }
    }
  }
}

extern "C" void kernel_launch(void* const* d_in, const int* in_sizes, int n_in,
                              void* d_out, int out_size, void* d_ws, size_t ws_size,
                              hipStream_t stream) {
  const float* rbf = (const float*)d_in[0];
  const float* sph = (const float*)d_in[1];
  const float* m   = (const float*)d_in[2];
  const float* W   = (const float*)d_in[3];
  const int* id_reduce = (const int*)d_in[4];
  const int* id_ragged = (const int*)d_in[5];
  float* out = (float*)d_out;

  int E = in_sizes[0] / (INTERM * SPH_N);   // 30000
  int nTrip = in_sizes[2] / EMB;            // 240000
  int nblk = (E + EB - 1) / EB;             // 469
  int Epad = nblk * EB;                     // 30016

  char* ws = (char*)d_ws;
  int* inv = (int*)ws;                                       // [0, 1 MB)
  unsigned short* W2T = (unsigned short*)(ws + (1u << 20));  // [1, 3 MB)
  float* sphT = (float*)(ws + (3u << 20));                   // [3, ~18.4 MB)

  (void)hipMemsetAsync(inv, 0xFF, (size_t)Epad * KMAX * sizeof(int), stream);
  k_build_inv<<<(nTrip + 255) / 256, 256, 0, stream>>>(id_reduce, id_ragged, inv, nTrip, E);
  k_w2t<<<(OUTD * KDIM) / 256, 256, 0, stream>>>(W, W2T);
  k_spht<<<(E * 128 + 255) / 256, 256, 0, stream>>>(sph, sphT, E);

  k_fused<<<nblk, NTHR, 0, stream>>>(rbf, sphT, m, inv, W2T, out, E);
}